// Round 12
// baseline (548.384 us; speedup 1.0000x reference)
//
#include <hip/hip_runtime.h>
#include <hip/hip_bf16.h>

#define N_NODES 50000
#define N_EDGES 800000
#define D_IN    128
#define D_H     64
#define SZ_C    4
#define D_ALL   (SZ_C * D_H)   // 256

typedef __bf16 bf16x8 __attribute__((ext_vector_type(8)));
typedef __bf16 bf16x2 __attribute__((ext_vector_type(2)));
typedef float  f32x4  __attribute__((ext_vector_type(4)));
typedef unsigned short us8 __attribute__((ext_vector_type(8)));

#if defined(__has_builtin)
#if __has_builtin(__builtin_amdgcn_fdot2_f32_bf16)
#define HAVE_DOT2 1
#else
#define HAVE_DOT2 0
#endif
#else
#define HAVE_DOT2 0
#endif

__device__ __forceinline__ float bf2f(unsigned short u) {
    return __uint_as_float(((unsigned)u) << 16);
}
__device__ __forceinline__ unsigned short f2bf(float f) {
    unsigned u = __float_as_uint(f);
    unsigned r = (u + 0x7fffu + ((u >> 16) & 1u)) >> 16;   // round-to-nearest-even
    return (unsigned short)r;
}

// acc += a.lo*c.lo + a.hi*c.hi, bf16 pairs in u32, f32 accumulate
__device__ __forceinline__ float dot2bf(unsigned ab, unsigned cc, float acc) {
#if HAVE_DOT2
    return __builtin_amdgcn_fdot2_f32_bf16(__builtin_bit_cast(bf16x2, ab),
                                           __builtin_bit_cast(bf16x2, cc), acc, false);
#else
    float a0 = __uint_as_float(ab << 16);
    float a1 = __uint_as_float(ab & 0xffff0000u);
    float c0 = __uint_as_float(cc << 16);
    float c1 = __uint_as_float(cc & 0xffff0000u);
    return acc + a0 * c0 + a1 * c1;
#endif
}

// ---------------- setup kernels ----------------
// deg_cnt counts REAL in-edges from 0 (zeroed by hipMemsetAsync); the +1
// self-loop is folded into dinv / padlen / self-slot downstream.

__global__ void f2bf_kernel(const float* __restrict__ in, unsigned short* __restrict__ out, int n4) {
    int i = blockIdx.x * blockDim.x + threadIdx.x;
    if (i < n4) {
        float4 v = ((const float4*)in)[i];
        ushort4 o;
        o.x = f2bf(v.x); o.y = f2bf(v.y); o.z = f2bf(v.z); o.w = f2bf(v.w);
        ((ushort4*)out)[i] = o;
    }
}

__global__ void hist_kernel(const int* __restrict__ dst, int* __restrict__ deg_cnt, int e) {
    int i = blockIdx.x * blockDim.x + threadIdx.x;
    if (i < e) atomicAdd(&deg_cnt[dst[i]], 1);
}

// scan phase 1 over padlen = ((deg+1)+7)&~7; also emits dinv = rsqrt(deg+1).
__global__ __launch_bounds__(1024) void scan_block_kernel(
    const int* __restrict__ deg_cnt, float* __restrict__ dinv,
    int* __restrict__ row_start, int* __restrict__ bsum, int n) {
    __shared__ int wsum[16];
    int t = threadIdx.x;
    int lane = t & 63, wv = t >> 6;
    int base = blockIdx.x * 1024;
    int v = 0;
    if (base + t < n) {
        int dg = deg_cnt[base + t];
        dinv[base + t] = rsqrtf((float)dg + 1.0f);
        v = (dg + 8) & ~7;
    }
    int x = v;
    #pragma unroll
    for (int off = 1; off < 64; off <<= 1) {
        int y = __shfl_up(x, off, 64);
        if (lane >= off) x += y;
    }
    if (lane == 63) wsum[wv] = x;
    __syncthreads();
    if (wv == 0 && lane < 16) {
        int ws = wsum[lane];
        #pragma unroll
        for (int off = 1; off < 16; off <<= 1) {
            int y = __shfl_up(ws, off, 64);
            if (lane >= off) ws += y;
        }
        wsum[lane] = ws;
    }
    __syncthreads();
    int wbase = (wv == 0) ? 0 : wsum[wv - 1];
    int incl = x + wbase;
    if (base + t < n) row_start[base + t + 1] = incl;
    if (t == 1023) bsum[blockIdx.x] = incl;
}

// scan phase 2+3 fused: every block butterfly-sums bsum[0..b-1] (nb<=64), adds.
__global__ __launch_bounds__(1024) void scan_add_kernel(
    const int* __restrict__ bsum, int* __restrict__ row_start, int n, int nb) {
    __shared__ int s_off;
    int b = blockIdx.x, t = threadIdx.x;
    if (t < 64) {
        int v = (t < nb && t < b) ? bsum[t] : 0;
        #pragma unroll
        for (int off = 1; off < 64; off <<= 1)
            v += __shfl_xor(v, off, 64);
        if (t == 0) s_off = v;
    }
    __syncthreads();
    int off = s_off;
    int i = b * 1024 + t;
    if (b == 0 && t == 0) row_start[0] = 0;
    if (i < n) row_start[i + 1] += off;
}

// One pass: scatter real edges (slots 0..deg-1 via cursor), self edge (slot deg),
// zero-coef padding to x8 (gathers row 0 -> L1-hot), 64 end-pad records.
__global__ void csr_fill_kernel(const int* __restrict__ src, const int* __restrict__ dst,
                                const int* __restrict__ row_start, int* __restrict__ cursor,
                                const int* __restrict__ deg_cnt, const float* __restrict__ dinv,
                                int2* __restrict__ csr_ec) {
    int i = blockIdx.x * blockDim.x + threadIdx.x;
    if (i < N_EDGES) {
        int d = dst[i];
        int s = src[i];
        int pos = row_start[d] + atomicAdd(&cursor[d], 1);
        int2 rec;
        rec.x = s;
        rec.y = (int)(unsigned)f2bf(dinv[s] * dinv[d]);
        csr_ec[pos] = rec;
    }
    if (i < N_NODES) {
        int s = row_start[i], e = row_start[i + 1];
        int selfslot = s + deg_cnt[i];
        float dv = dinv[i];
        int2 rec;
        rec.x = i;
        rec.y = (int)(unsigned)f2bf(dv * dv);
        csr_ec[selfslot] = rec;
        rec.x = 0;
        rec.y = 0;
        for (int k = selfslot + 1; k < e; ++k) csr_ec[k] = rec;
    }
    if (i < 64) {
        int2 z0; z0.x = 0; z0.y = 0;
        csr_ec[row_start[N_NODES] + i] = z0;
    }
}

// Pack all three weight tensors into MFMA B-frag layout; blockIdx.y selects tensor.
__global__ void pack_all_kernel(const float* __restrict__ W0, const float* __restrict__ Wl,
                                unsigned short* __restrict__ W0p,
                                unsigned short* __restrict__ Wl0p,
                                unsigned short* __restrict__ Wl1p) {
    int tid = blockIdx.x * blockDim.x + threadIdx.x;
    int which = blockIdx.y;
    const float* W;
    unsigned short* P;
    int ksteps, total, chanStride;
    if (which == 0)      { W = W0;             P = W0p;  ksteps = 4; total = SZ_C * 4 * 4 * 512; chanStride = D_IN * D_H; }
    else if (which == 1) { W = Wl;             P = Wl0p; ksteps = 2; total = SZ_C * 2 * 4 * 512; chanStride = 2 * D_H * D_H; }
    else                 { W = Wl + D_H * D_H; P = Wl1p; ksteps = 2; total = SZ_C * 2 * 4 * 512; chanStride = 2 * D_H * D_H; }
    if (tid >= total) return;
    int j = tid & 7;
    int lane = (tid >> 3) & 63;
    int nn = (tid >> 9) & 3;
    int cks = tid >> 11;
    int ks = cks % ksteps;
    int c = cks / ksteps;
    int k = ks * 32 + (lane >> 4) * 8 + j;
    int d = nn * 16 + (lane & 15);
    P[tid] = f2bf(W[(size_t)c * chanStride + (size_t)k * 64 + d]);
}

// ---------------- XCD-sliced aggregation ----------------
// z[i, slice] = sum_j coef_j * h[src_j, slice], slice = 32 dims (64 B).
// grid = 12500 * 8; slice = blockIdx.x % 8 -> with the empirical round-robin
// XCD = blockIdx % 8, each XCD gathers only its own N*64B = 3.2 MB slice of h
// (L2-resident). NSLICE=4 for RS=128 (2 XCDs per slice). 4 waves/block, wave =
// one node-slice. Lane = (edge group g 0..15, dim sublane sl 0..3); 32 edges
// per iteration (jA = j0+g, jB = j0+16+g) with per-edge coef masking; rows are
// x8-padded, array end-padded by 64 records -> all reads in bounds.
// Performance heuristic only: if XCD mapping differs, result is still correct.

template<int RS, int NSLICE>   // (256,8) or (128,4)
__global__ __launch_bounds__(256) void agg_slice_kernel(
    const unsigned short* __restrict__ h,   // bf16 [N, RS]
    const int* __restrict__ row_start,
    const int2* __restrict__ csr_ec,
    unsigned short* __restrict__ z)         // bf16 [N, RS]
{
    int b = blockIdx.x;
    int slice = (b & 7) % NSLICE;
    int nb = b >> 3;                 // node group
    int w = threadIdx.x >> 6;
    int lane = threadIdx.x & 63;
    int i = nb * 4 + w;
    int g = lane >> 2;               // edge group 0..15
    int sl = lane & 3;               // dim sublane 0..3
    int s = row_start[i], e = row_start[i + 1];
    const unsigned short* hb = h + slice * 32 + sl * 8;
    float acc[8] = {};

    for (int j0 = s; j0 < e; j0 += 32) {
        int jA = j0 + g, jB = j0 + 16 + g;
        int2 rA = csr_ec[jA];        // row padding / end pad keep these valid
        int2 rB = csr_ec[jB];
        unsigned cc = ((unsigned)rA.y & 0xffffu) | ((unsigned)rB.y << 16);
        if (jA >= e) cc &= 0xffff0000u;   // mask coef A
        if (jB >= e) cc &= 0x0000ffffu;   // mask coef B
        uint4 va = *(const uint4*)(hb + (size_t)rA.x * RS);
        uint4 vb = *(const uint4*)(hb + (size_t)rB.x * RS);
        const unsigned* p0 = (const unsigned*)&va;
        const unsigned* p1 = (const unsigned*)&vb;
        #pragma unroll
        for (int q = 0; q < 4; ++q) {
            unsigned lo = __builtin_amdgcn_perm(p0[q], p1[q], 0x01000504u);
            unsigned hi = __builtin_amdgcn_perm(p0[q], p1[q], 0x03020706u);
            acc[2*q]   = dot2bf(lo, cc, acc[2*q]);
            acc[2*q+1] = dot2bf(hi, cc, acc[2*q+1]);
        }
    }
    // reduce across the 16 edge groups (stride-4 lanes)
    #pragma unroll
    for (int off = 4; off < 64; off <<= 1)
        #pragma unroll
        for (int q = 0; q < 8; ++q)
            acc[q] += __shfl_xor(acc[q], off, 64);
    if (g == 0) {
        us8 o;
        #pragma unroll
        for (int q = 0; q < 8; ++q) o[q] = f2bf(acc[q]);
        *(us8*)(z + (size_t)i * RS + slice * 32 + sl * 8) = o;
    }
}

// ---------------- MFMA GEMM + fused epilogue ----------------
// h' = relu(z@W + b) + (z@W + b); EPIL=0: write bf16 h'; EPIL=1: LayerNorm -> fp32 out

template<int EPIL>
__global__ __launch_bounds__(256) void mfma_gemm_kernel(
    const unsigned short* __restrict__ A, int lda, int aChanOff,
    const unsigned short* __restrict__ Bpack, int ksteps,
    const float* __restrict__ bias, int biasChanStride,
    unsigned short* __restrict__ Cbf,
    float* __restrict__ outF, const float* __restrict__ gamma, const float* __restrict__ beta,
    int M)
{
    int c = blockIdx.y;
    int m0 = blockIdx.x * 64;
    int w = threadIdx.x >> 6, lane = threadIdx.x & 63;
    int arow = m0 + w * 16 + (lane & 15);
    int arow_c = (arow < M) ? arow : (M - 1);
    const unsigned short* Ap = A + (size_t)arow_c * lda + aChanOff * c + (lane >> 4) * 8;
    const unsigned short* Bp = Bpack + ((size_t)c * ksteps * 4) * 512 + (size_t)lane * 8;
    f32x4 acc[4] = {};
    for (int ks = 0; ks < ksteps; ++ks) {
        bf16x8 af = *(const bf16x8*)(Ap + ks * 32);
        const unsigned short* b = Bp + (size_t)ks * 2048;
        #pragma unroll
        for (int n = 0; n < 4; ++n) {
            bf16x8 bfr = *(const bf16x8*)(b + n * 512);
            acc[n] = __builtin_amdgcn_mfma_f32_16x16x32_bf16(af, bfr, acc[n], 0, 0, 0);
        }
    }
    int col = lane & 15;
    int rbase = m0 + w * 16 + (lane >> 4) * 4;
    float hv[4][4];
    #pragma unroll
    for (int n = 0; n < 4; ++n) {
        float bv = bias[c * biasChanStride + n * 16 + col];
        #pragma unroll
        for (int r = 0; r < 4; ++r) {
            float a = acc[n][r] + bv;
            hv[n][r] = (a > 0.f) ? a + a : a;   // relu(a) + a
        }
    }
    if (EPIL == 0) {
        #pragma unroll
        for (int n = 0; n < 4; ++n) {
            #pragma unroll
            for (int r = 0; r < 4; ++r) {
                int rr = rbase + r;
                if (rr < M) Cbf[(size_t)rr * D_ALL + c * 64 + n * 16 + col] = f2bf(hv[n][r]);
            }
        }
    } else {
        float sum[4], sq[4];
        #pragma unroll
        for (int r = 0; r < 4; ++r) {
            sum[r] = hv[0][r] + hv[1][r] + hv[2][r] + hv[3][r];
            sq[r] = hv[0][r]*hv[0][r] + hv[1][r]*hv[1][r] + hv[2][r]*hv[2][r] + hv[3][r]*hv[3][r];
        }
        #pragma unroll
        for (int off = 1; off < 16; off <<= 1) {
            #pragma unroll
            for (int r = 0; r < 4; ++r) {
                sum[r] += __shfl_xor(sum[r], off, 64);
                sq[r]  += __shfl_xor(sq[r], off, 64);
            }
        }
        #pragma unroll
        for (int n = 0; n < 4; ++n) {
            float gv = gamma[n * 16 + col];
            float bv2 = beta[n * 16 + col];
            #pragma unroll
            for (int r = 0; r < 4; ++r) {
                float mu = sum[r] * (1.f / 64.f);
                float var = sq[r] * (1.f / 64.f) - mu * mu;
                float rinv = rsqrtf(var + 1e-6f);
                int rr = rbase + r;
                if (rr < M)
                    outF[(size_t)c * N_NODES * D_H + (size_t)rr * D_H + n * 16 + col] =
                        (hv[n][r] - mu) * rinv * gv + bv2;
            }
        }
    }
}

// ---------------- launch ----------------

extern "C" void kernel_launch(void* const* d_in, const int* in_sizes, int n_in,
                              void* d_out, int out_size, void* d_ws, size_t ws_size,
                              hipStream_t stream) {
    const float* x     = (const float*)d_in[0];
    const int*   edge  = (const int*)d_in[1];
    const float* W0    = (const float*)d_in[3];
    const float* b0    = (const float*)d_in[4];
    const float* Wl    = (const float*)d_in[5];
    const float* bl    = (const float*)d_in[6];
    const float* gamma = (const float*)d_in[7];
    const float* beta  = (const float*)d_in[8];
    float* out = (float*)d_out;

    const int* e_src = edge;            // edge[0]
    const int* e_dst = edge + N_EDGES;  // edge[1]

    char* ws = (char*)d_ws;
    size_t off = 0;
    auto alloc = [&](size_t bytes) -> void* {
        void* p = ws + off;
        off = (off + bytes + 255) & ~(size_t)255;
        return p;
    };
    const int NE_MAX = N_EDGES + 8 * N_NODES + 64;   // x8-padded rows + end pad
    const int NB_SCAN = (N_NODES + 1023) / 1024;     // 49
    int*   deg_cur   = (int*)  alloc(sizeof(int)   * 2 * N_NODES);  // deg | cursor
    int*   deg_cnt   = deg_cur;
    int*   cursor    = deg_cur + N_NODES;
    int*   row_start = (int*)  alloc(sizeof(int)   * (N_NODES + 1));
    int*   bsum      = (int*)  alloc(sizeof(int)   * 64);
    float* dinv      = (float*)alloc(sizeof(float) * N_NODES);
    int2*  csr_ec    = (int2*) alloc(sizeof(int2)  * NE_MAX);
    unsigned short* x_bf  = (unsigned short*)alloc(sizeof(unsigned short) * (size_t)N_NODES * D_IN);
    unsigned short* W0p   = (unsigned short*)alloc(sizeof(unsigned short) * SZ_C * 4 * 4 * 512);
    unsigned short* Wl0p  = (unsigned short*)alloc(sizeof(unsigned short) * SZ_C * 2 * 4 * 512);
    unsigned short* Wl1p  = (unsigned short*)alloc(sizeof(unsigned short) * SZ_C * 2 * 4 * 512);
    unsigned short* zbuf  = (unsigned short*)alloc(sizeof(unsigned short) * (size_t)N_NODES * D_ALL);
    unsigned short* h_bf  = (unsigned short*)alloc(sizeof(unsigned short) * (size_t)N_NODES * D_ALL);

    const int nb_e = (N_EDGES + 255) / 256;
    const int n4   = N_NODES * D_IN / 4;

    hipMemsetAsync(deg_cur, 0, sizeof(int) * 2 * N_NODES, stream);
    f2bf_kernel<<<(n4 + 255) / 256, 256, 0, stream>>>(x, x_bf, n4);
    hist_kernel<<<nb_e, 256, 0, stream>>>(e_dst, deg_cnt, N_EDGES);
    scan_block_kernel<<<NB_SCAN, 1024, 0, stream>>>(deg_cnt, dinv, row_start, bsum, N_NODES);
    scan_add_kernel<<<NB_SCAN, 1024, 0, stream>>>(bsum, row_start, N_NODES, NB_SCAN);
    csr_fill_kernel<<<nb_e, 256, 0, stream>>>(e_src, e_dst, row_start, cursor,
                                              deg_cnt, dinv, csr_ec);
    {
        dim3 pgrid((SZ_C * 4 * 4 * 512 + 255) / 256, 3);
        pack_all_kernel<<<pgrid, 256, 0, stream>>>(W0, Wl, W0p, Wl0p, Wl1p);
    }

    dim3 ggrid((N_NODES + 63) / 64, SZ_C);
    const int agg_grid = (N_NODES / 4) * 8;   // 100000 blocks: node-group x 8 (XCD slice)

    // layer 0: z = agg(x_bf) [N,128]; h = relures(z@W0 + b0) [N,256]
    agg_slice_kernel<D_IN, 4><<<agg_grid, 256, 0, stream>>>(x_bf, row_start, csr_ec, zbuf);
    mfma_gemm_kernel<0><<<ggrid, 256, 0, stream>>>(zbuf, D_IN, 0, W0p, 4,
                                                   b0, 64, h_bf, nullptr, nullptr, nullptr, N_NODES);
    // layer 1: z = agg(h) [N,256]; h = relures(z@Wl0 + bl0)
    agg_slice_kernel<D_ALL, 8><<<agg_grid, 256, 0, stream>>>(h_bf, row_start, csr_ec, zbuf);
    mfma_gemm_kernel<0><<<ggrid, 256, 0, stream>>>(zbuf, D_ALL, 64, Wl0p, 2,
                                                   bl, 2 * 64, h_bf, nullptr, nullptr, nullptr, N_NODES);
    // layer 2: z = agg(h); out = LN(relures(z@Wl1 + bl1)) -> d_out fp32
    agg_slice_kernel<D_ALL, 8><<<agg_grid, 256, 0, stream>>>(h_bf, row_start, csr_ec, zbuf);
    mfma_gemm_kernel<1><<<ggrid, 256, 0, stream>>>(zbuf, D_ALL, 64, Wl1p, 2,
                                                   bl + 64, 2 * 64, nullptr, out, gamma, beta, N_NODES);
}

// Round 13
// 292.846 us; speedup vs baseline: 1.8726x; 1.8726x over previous
//
#include <hip/hip_runtime.h>
#include <hip/hip_bf16.h>

#define N_NODES 50000
#define N_EDGES 800000
#define D_IN    128
#define D_H     64
#define SZ_C    4
#define D_ALL   (SZ_C * D_H)   // 256

typedef __bf16 bf16x8 __attribute__((ext_vector_type(8)));
typedef __bf16 bf16x2 __attribute__((ext_vector_type(2)));
typedef float  f32x4  __attribute__((ext_vector_type(4)));
typedef unsigned short us8 __attribute__((ext_vector_type(8)));

#if defined(__has_builtin)
#if __has_builtin(__builtin_amdgcn_fdot2_f32_bf16)
#define HAVE_DOT2 1
#else
#define HAVE_DOT2 0
#endif
#else
#define HAVE_DOT2 0
#endif

__device__ __forceinline__ float bf2f(unsigned short u) {
    return __uint_as_float(((unsigned)u) << 16);
}
__device__ __forceinline__ unsigned short f2bf(float f) {
    unsigned u = __float_as_uint(f);
    unsigned r = (u + 0x7fffu + ((u >> 16) & 1u)) >> 16;   // round-to-nearest-even
    return (unsigned short)r;
}

// acc += a.lo*c.lo + a.hi*c.hi, bf16 pairs in u32, f32 accumulate
__device__ __forceinline__ float dot2bf(unsigned ab, unsigned cc, float acc) {
#if HAVE_DOT2
    return __builtin_amdgcn_fdot2_f32_bf16(__builtin_bit_cast(bf16x2, ab),
                                           __builtin_bit_cast(bf16x2, cc), acc, false);
#else
    float a0 = __uint_as_float(ab << 16);
    float a1 = __uint_as_float(ab & 0xffff0000u);
    float c0 = __uint_as_float(cc << 16);
    float c1 = __uint_as_float(cc & 0xffff0000u);
    return acc + a0 * c0 + a1 * c1;
#endif
}

// ---------------- setup kernels ----------------
// deg_cnt counts REAL in-edges from 0 (zeroed by hipMemsetAsync); the +1
// self-loop is folded into dinv / padlen / self-slot downstream.

__global__ void f2bf_kernel(const float* __restrict__ in, unsigned short* __restrict__ out, int n4) {
    int i = blockIdx.x * blockDim.x + threadIdx.x;
    if (i < n4) {
        float4 v = ((const float4*)in)[i];
        ushort4 o;
        o.x = f2bf(v.x); o.y = f2bf(v.y); o.z = f2bf(v.z); o.w = f2bf(v.w);
        ((ushort4*)out)[i] = o;
    }
}

__global__ void hist_kernel(const int* __restrict__ dst, int* __restrict__ deg_cnt, int e) {
    int i = blockIdx.x * blockDim.x + threadIdx.x;
    if (i < e) atomicAdd(&deg_cnt[dst[i]], 1);
}

// scan phase 1 over padlen = ((deg+1)+7)&~7; also emits dinv = rsqrt(deg+1).
__global__ __launch_bounds__(1024) void scan_block_kernel(
    const int* __restrict__ deg_cnt, float* __restrict__ dinv,
    int* __restrict__ row_start, int* __restrict__ bsum, int n) {
    __shared__ int wsum[16];
    int t = threadIdx.x;
    int lane = t & 63, wv = t >> 6;
    int base = blockIdx.x * 1024;
    int v = 0;
    if (base + t < n) {
        int dg = deg_cnt[base + t];
        dinv[base + t] = rsqrtf((float)dg + 1.0f);
        v = (dg + 8) & ~7;
    }
    int x = v;
    #pragma unroll
    for (int off = 1; off < 64; off <<= 1) {
        int y = __shfl_up(x, off, 64);
        if (lane >= off) x += y;
    }
    if (lane == 63) wsum[wv] = x;
    __syncthreads();
    if (wv == 0 && lane < 16) {
        int ws = wsum[lane];
        #pragma unroll
        for (int off = 1; off < 16; off <<= 1) {
            int y = __shfl_up(ws, off, 64);
            if (lane >= off) ws += y;
        }
        wsum[lane] = ws;
    }
    __syncthreads();
    int wbase = (wv == 0) ? 0 : wsum[wv - 1];
    int incl = x + wbase;
    if (base + t < n) row_start[base + t + 1] = incl;
    if (t == 1023) bsum[blockIdx.x] = incl;
}

// scan phase 2+3 fused: every block butterfly-sums bsum[0..b-1] (nb<=64), adds.
__global__ __launch_bounds__(1024) void scan_add_kernel(
    const int* __restrict__ bsum, int* __restrict__ row_start, int n, int nb) {
    __shared__ int s_off;
    int b = blockIdx.x, t = threadIdx.x;
    if (t < 64) {
        int v = (t < nb && t < b) ? bsum[t] : 0;
        #pragma unroll
        for (int off = 1; off < 64; off <<= 1)
            v += __shfl_xor(v, off, 64);
        if (t == 0) s_off = v;
    }
    __syncthreads();
    int off = s_off;
    int i = b * 1024 + t;
    if (b == 0 && t == 0) row_start[0] = 0;
    if (i < n) row_start[i + 1] += off;
}

// Fused CSR build + weight packing; blockIdx.y selects the job.
// y==0: scatter real edges (slots 0..deg-1 via cursor), self edge (slot deg),
//       zero-coef padding to x8 (gathers row 0 -> L1-hot), 32 end-pad records.
// y==1: pack W0/Wl0/Wl1 (fp32) into the MFMA B-frag layout:
//       P[((c*ksteps+ks)*4+nn)*512 + lane*8 + j]
//         = bf16(W[c][ks*32 + (lane>>4)*8 + j][nn*16 + (lane&15)])
__global__ void csr_pack_kernel(const int* __restrict__ src, const int* __restrict__ dst,
                                const int* __restrict__ row_start, int* __restrict__ cursor,
                                const int* __restrict__ deg_cnt, const float* __restrict__ dinv,
                                int2* __restrict__ csr_ec,
                                const float* __restrict__ W0, const float* __restrict__ Wl,
                                unsigned short* __restrict__ W0p,
                                unsigned short* __restrict__ Wl0p,
                                unsigned short* __restrict__ Wl1p) {
    int i = blockIdx.x * blockDim.x + threadIdx.x;
    if (blockIdx.y == 0) {
        if (i < N_EDGES) {
            int d = dst[i];
            int s = src[i];
            int pos = row_start[d] + atomicAdd(&cursor[d], 1);
            int2 rec;
            rec.x = s;
            rec.y = (int)(unsigned)f2bf(dinv[s] * dinv[d]);
            csr_ec[pos] = rec;
        }
        if (i < N_NODES) {
            int s = row_start[i], e = row_start[i + 1];
            int selfslot = s + deg_cnt[i];
            float dv = dinv[i];
            int2 rec;
            rec.x = i;
            rec.y = (int)(unsigned)f2bf(dv * dv);
            csr_ec[selfslot] = rec;
            rec.x = 0;
            rec.y = 0;
            for (int k = selfslot + 1; k < e; ++k) csr_ec[k] = rec;
        }
        if (i < 32) {
            int2 z0; z0.x = 0; z0.y = 0;
            csr_ec[row_start[N_NODES] + i] = z0;
        }
    } else {
        // pack: W0p = 32768 elems, Wl0p/Wl1p = 16384 each
        const float* W;
        unsigned short* P;
        int ksteps, chanStride, tid;
        if (i < 32768)      { W = W0;             P = W0p;  ksteps = 4; chanStride = D_IN * D_H;    tid = i; }
        else if (i < 49152) { W = Wl;             P = Wl0p; ksteps = 2; chanStride = 2 * D_H * D_H; tid = i - 32768; }
        else if (i < 65536) { W = Wl + D_H * D_H; P = Wl1p; ksteps = 2; chanStride = 2 * D_H * D_H; tid = i - 49152; }
        else return;
        int j = tid & 7;
        int lane = (tid >> 3) & 63;
        int nn = (tid >> 9) & 3;
        int cks = tid >> 11;
        int ks = cks % ksteps;
        int c = cks / ksteps;
        int k = ks * 32 + (lane >> 4) * 8 + j;
        int d = nn * 16 + (lane & 15);
        P[tid] = f2bf(W[(size_t)c * chanStride + (size_t)k * 64 + d]);
    }
}

// ---------------- aggregation: z[i] = sum_j coef_j * h[src_j] ----------------
// One wave per node (4 nodes / 256-thread block). lane = (group g, sublane sl);
// each lane loads 16 B (8 dims). 4 record-pair slots per iteration for BOTH
// widths -> 8 row-gathers in flight per lane (RS=128: 32 edges/iter, RS=256: 16).
// Next iteration's records loaded under current VALU. Rows padded to x8, array
// end-padded by 32 records. Tail is STATICALLY unrolled (compile-time indices
// only -- runtime-indexed private arrays get promoted to LDS, 16KB + bank
// conflicts, round-10 regression).

template<int RS>   // 128 (x / layer0) or 256 (h)
__global__ __launch_bounds__(256) void agg_kernel(
    const unsigned short* __restrict__ h,   // bf16 [N, RS]
    const int* __restrict__ row_start,
    const int2* __restrict__ csr_ec,
    unsigned short* __restrict__ z)         // bf16 [N, RS]
{
    constexpr int LPR = RS / 8;      // lanes per row: 16 or 32
    constexpr int G = 64 / LPR;      // edge-pair groups: 4 or 2
    constexpr int EPI = 2 * G;       // edges per slot: 8 or 4
    constexpr int ITER_E = 4 * EPI;  // edges per iteration: 32 or 16
    int w = threadIdx.x >> 6;
    int lane = threadIdx.x & 63;
    int i = blockIdx.x * 4 + w;
    int g = lane / LPR;
    int sl = lane % LPR;
    int s = row_start[i], e = row_start[i + 1];
    float acc[8] = {};
    const unsigned short* hb = h + sl * 8;

    int4 r0 = *(const int4*)(csr_ec + s + 0 * EPI + 2 * g);
    int4 r1 = *(const int4*)(csr_ec + s + 1 * EPI + 2 * g);
    int4 r2 = *(const int4*)(csr_ec + s + 2 * EPI + 2 * g);
    int4 r3 = *(const int4*)(csr_ec + s + 3 * EPI + 2 * g);

    int j0 = s;
    for (; j0 + ITER_E <= e; j0 += ITER_E) {
        // issue 8 row-gathers for current records
        uint4 a0 = *(const uint4*)(hb + (size_t)r0.x * RS);
        uint4 b0 = *(const uint4*)(hb + (size_t)r0.z * RS);
        uint4 a1 = *(const uint4*)(hb + (size_t)r1.x * RS);
        uint4 b1 = *(const uint4*)(hb + (size_t)r1.z * RS);
        uint4 a2 = *(const uint4*)(hb + (size_t)r2.x * RS);
        uint4 b2 = *(const uint4*)(hb + (size_t)r2.z * RS);
        uint4 a3 = *(const uint4*)(hb + (size_t)r3.x * RS);
        uint4 b3 = *(const uint4*)(hb + (size_t)r3.z * RS);
        // issue next iteration's record loads (end-pad keeps this in bounds)
        int4 n0 = *(const int4*)(csr_ec + (j0 + ITER_E) + 0 * EPI + 2 * g);
        int4 n1 = *(const int4*)(csr_ec + (j0 + ITER_E) + 1 * EPI + 2 * g);
        int4 n2 = *(const int4*)(csr_ec + (j0 + ITER_E) + 2 * EPI + 2 * g);
        int4 n3 = *(const int4*)(csr_ec + (j0 + ITER_E) + 3 * EPI + 2 * g);
        // compute (macro keeps all indices compile-time)
#define DO_SLOT(RR, AA, BB) do {                                                         \
        unsigned cc = __builtin_amdgcn_perm((unsigned)RR.y, (unsigned)RR.w, 0x01000504u);\
        const unsigned* p0 = (const unsigned*)&AA;                                       \
        const unsigned* p1 = (const unsigned*)&BB;                                       \
        _Pragma("unroll")                                                                \
        for (int q = 0; q < 4; ++q) {                                                    \
            unsigned lo = __builtin_amdgcn_perm(p0[q], p1[q], 0x01000504u);              \
            unsigned hi = __builtin_amdgcn_perm(p0[q], p1[q], 0x03020706u);              \
            acc[2*q]   = dot2bf(lo, cc, acc[2*q]);                                       \
            acc[2*q+1] = dot2bf(hi, cc, acc[2*q+1]);                                     \
        } } while (0)
        DO_SLOT(r0, a0, b0);
        DO_SLOT(r1, a1, b1);
        DO_SLOT(r2, a2, b2);
        DO_SLOT(r3, a3, b3);
        r0 = n0; r1 = n1; r2 = n2; r3 = n3;
    }
    // tail: 0..3 chunks of EPI edges; records already in r0..r2. Static guards.
    int rem = e - j0;
    if (rem >= 1 * EPI) {
        uint4 a0 = *(const uint4*)(hb + (size_t)r0.x * RS);
        uint4 b0 = *(const uint4*)(hb + (size_t)r0.z * RS);
        DO_SLOT(r0, a0, b0);
    }
    if (rem >= 2 * EPI) {
        uint4 a1 = *(const uint4*)(hb + (size_t)r1.x * RS);
        uint4 b1 = *(const uint4*)(hb + (size_t)r1.z * RS);
        DO_SLOT(r1, a1, b1);
    }
    if (rem >= 3 * EPI) {
        uint4 a2 = *(const uint4*)(hb + (size_t)r2.x * RS);
        uint4 b2 = *(const uint4*)(hb + (size_t)r2.z * RS);
        DO_SLOT(r2, a2, b2);
    }
#undef DO_SLOT
    // butterfly-combine across edge groups
    #pragma unroll
    for (int off = LPR; off < 64; off <<= 1)
        #pragma unroll
        for (int q = 0; q < 8; ++q)
            acc[q] += __shfl_xor(acc[q], off, 64);
    if (g == 0) {
        us8 o;
        #pragma unroll
        for (int q = 0; q < 8; ++q) o[q] = f2bf(acc[q]);
        *(us8*)(z + (size_t)i * RS + sl * 8) = o;
    }
}

// ---------------- MFMA GEMM + fused epilogue ----------------
// h' = relu(z@W + b) + (z@W + b); EPIL=0: write bf16 h'; EPIL=1: LayerNorm -> fp32 out

template<int EPIL>
__global__ __launch_bounds__(256) void mfma_gemm_kernel(
    const unsigned short* __restrict__ A, int lda, int aChanOff,
    const unsigned short* __restrict__ Bpack, int ksteps,
    const float* __restrict__ bias, int biasChanStride,
    unsigned short* __restrict__ Cbf,
    float* __restrict__ outF, const float* __restrict__ gamma, const float* __restrict__ beta,
    int M)
{
    int c = blockIdx.y;
    int m0 = blockIdx.x * 64;
    int w = threadIdx.x >> 6, lane = threadIdx.x & 63;
    int arow = m0 + w * 16 + (lane & 15);
    int arow_c = (arow < M) ? arow : (M - 1);
    const unsigned short* Ap = A + (size_t)arow_c * lda + aChanOff * c + (lane >> 4) * 8;
    const unsigned short* Bp = Bpack + ((size_t)c * ksteps * 4) * 512 + (size_t)lane * 8;
    f32x4 acc[4] = {};
    for (int ks = 0; ks < ksteps; ++ks) {
        bf16x8 af = *(const bf16x8*)(Ap + ks * 32);
        const unsigned short* b = Bp + (size_t)ks * 2048;
        #pragma unroll
        for (int n = 0; n < 4; ++n) {
            bf16x8 bfr = *(const bf16x8*)(b + n * 512);
            acc[n] = __builtin_amdgcn_mfma_f32_16x16x32_bf16(af, bfr, acc[n], 0, 0, 0);
        }
    }
    int col = lane & 15;
    int rbase = m0 + w * 16 + (lane >> 4) * 4;
    float hv[4][4];
    #pragma unroll
    for (int n = 0; n < 4; ++n) {
        float bv = bias[c * biasChanStride + n * 16 + col];
        #pragma unroll
        for (int r = 0; r < 4; ++r) {
            float a = acc[n][r] + bv;
            hv[n][r] = (a > 0.f) ? a + a : a;   // relu(a) + a
        }
    }
    if (EPIL == 0) {
        #pragma unroll
        for (int n = 0; n < 4; ++n) {
            #pragma unroll
            for (int r = 0; r < 4; ++r) {
                int rr = rbase + r;
                if (rr < M) Cbf[(size_t)rr * D_ALL + c * 64 + n * 16 + col] = f2bf(hv[n][r]);
            }
        }
    } else {
        float sum[4], sq[4];
        #pragma unroll
        for (int r = 0; r < 4; ++r) {
            sum[r] = hv[0][r] + hv[1][r] + hv[2][r] + hv[3][r];
            sq[r] = hv[0][r]*hv[0][r] + hv[1][r]*hv[1][r] + hv[2][r]*hv[2][r] + hv[3][r]*hv[3][r];
        }
        #pragma unroll
        for (int off = 1; off < 16; off <<= 1) {
            #pragma unroll
            for (int r = 0; r < 4; ++r) {
                sum[r] += __shfl_xor(sum[r], off, 64);
                sq[r]  += __shfl_xor(sq[r], off, 64);
            }
        }
        #pragma unroll
        for (int n = 0; n < 4; ++n) {
            float gv = gamma[n * 16 + col];
            float bv2 = beta[n * 16 + col];
            #pragma unroll
            for (int r = 0; r < 4; ++r) {
                float mu = sum[r] * (1.f / 64.f);
                float var = sq[r] * (1.f / 64.f) - mu * mu;
                float rinv = rsqrtf(var + 1e-6f);
                int rr = rbase + r;
                if (rr < M)
                    outF[(size_t)c * N_NODES * D_H + (size_t)rr * D_H + n * 16 + col] =
                        (hv[n][r] - mu) * rinv * gv + bv2;
            }
        }
    }
}

// ---------------- launch ----------------

extern "C" void kernel_launch(void* const* d_in, const int* in_sizes, int n_in,
                              void* d_out, int out_size, void* d_ws, size_t ws_size,
                              hipStream_t stream) {
    const float* x     = (const float*)d_in[0];
    const int*   edge  = (const int*)d_in[1];
    const float* W0    = (const float*)d_in[3];
    const float* b0    = (const float*)d_in[4];
    const float* Wl    = (const float*)d_in[5];
    const float* bl    = (const float*)d_in[6];
    const float* gamma = (const float*)d_in[7];
    const float* beta  = (const float*)d_in[8];
    float* out = (float*)d_out;

    const int* e_src = edge;            // edge[0]
    const int* e_dst = edge + N_EDGES;  // edge[1]

    char* ws = (char*)d_ws;
    size_t off = 0;
    auto alloc = [&](size_t bytes) -> void* {
        void* p = ws + off;
        off = (off + bytes + 255) & ~(size_t)255;
        return p;
    };
    const int NE_MAX = N_EDGES + 8 * N_NODES + 32;   // x8-padded rows + end pad
    const int NB_SCAN = (N_NODES + 1023) / 1024;     // 49
    int*   deg_cur   = (int*)  alloc(sizeof(int)   * 2 * N_NODES);  // deg | cursor
    int*   deg_cnt   = deg_cur;
    int*   cursor    = deg_cur + N_NODES;
    int*   row_start = (int*)  alloc(sizeof(int)   * (N_NODES + 1));
    int*   bsum      = (int*)  alloc(sizeof(int)   * 64);
    float* dinv      = (float*)alloc(sizeof(float) * N_NODES);
    int2*  csr_ec    = (int2*) alloc(sizeof(int2)  * NE_MAX);
    unsigned short* x_bf  = (unsigned short*)alloc(sizeof(unsigned short) * (size_t)N_NODES * D_IN);
    unsigned short* W0p   = (unsigned short*)alloc(sizeof(unsigned short) * SZ_C * 4 * 4 * 512);
    unsigned short* Wl0p  = (unsigned short*)alloc(sizeof(unsigned short) * SZ_C * 2 * 4 * 512);
    unsigned short* Wl1p  = (unsigned short*)alloc(sizeof(unsigned short) * SZ_C * 2 * 4 * 512);
    unsigned short* zbuf  = (unsigned short*)alloc(sizeof(unsigned short) * (size_t)N_NODES * D_ALL);
    unsigned short* h_bf  = (unsigned short*)alloc(sizeof(unsigned short) * (size_t)N_NODES * D_ALL);

    const int nb_e = (N_EDGES + 255) / 256;
    const int n4   = N_NODES * D_IN / 4;

    hipMemsetAsync(deg_cur, 0, sizeof(int) * 2 * N_NODES, stream);
    f2bf_kernel<<<(n4 + 255) / 256, 256, 0, stream>>>(x, x_bf, n4);
    hist_kernel<<<nb_e, 256, 0, stream>>>(e_dst, deg_cnt, N_EDGES);
    scan_block_kernel<<<NB_SCAN, 1024, 0, stream>>>(deg_cnt, dinv, row_start, bsum, N_NODES);
    scan_add_kernel<<<NB_SCAN, 1024, 0, stream>>>(bsum, row_start, N_NODES, NB_SCAN);
    {
        dim3 cgrid(nb_e, 2);
        csr_pack_kernel<<<cgrid, 256, 0, stream>>>(e_src, e_dst, row_start, cursor,
                                                   deg_cnt, dinv, csr_ec,
                                                   W0, Wl, W0p, Wl0p, Wl1p);
    }

    dim3 ggrid((N_NODES + 63) / 64, SZ_C);
    const int agg_grid = N_NODES / 4;  // 12500 blocks x 256 threads

    // layer 0: z = agg(x_bf) [N,128]; h = relures(z@W0 + b0) [N,256]
    agg_kernel<D_IN><<<agg_grid, 256, 0, stream>>>(x_bf, row_start, csr_ec, zbuf);
    mfma_gemm_kernel<0><<<ggrid, 256, 0, stream>>>(zbuf, D_IN, 0, W0p, 4,
                                                   b0, 64, h_bf, nullptr, nullptr, nullptr, N_NODES);
    // layer 1: z = agg(h) [N,256]; h = relures(z@Wl0 + bl0)
    agg_kernel<D_ALL><<<agg_grid, 256, 0, stream>>>(h_bf, row_start, csr_ec, zbuf);
    mfma_gemm_kernel<0><<<ggrid, 256, 0, stream>>>(zbuf, D_ALL, 64, Wl0p, 2,
                                                   bl, 2 * 64, h_bf, nullptr, nullptr, nullptr, N_NODES);
    // layer 2: z = agg(h); out = LN(relures(z@Wl1 + bl1)) -> d_out fp32
    agg_kernel<D_ALL><<<agg_grid, 256, 0, stream>>>(h_bf, row_start, csr_ec, zbuf);
    mfma_gemm_kernel<1><<<ggrid, 256, 0, stream>>>(zbuf, D_ALL, 64, Wl1p, 2,
                                                   bl + 64, 2 * 64, nullptr, out, gamma, beta, N_NODES);
}